// Round 1
// baseline (538.492 us; speedup 1.0000x reference)
//
#include <hip/hip_runtime.h>
#include <hip/hip_bf16.h>

#define H 256
#define NN 128
#define BB 16

typedef __attribute__((ext_vector_type(8))) __bf16 bf16x8;
typedef __attribute__((ext_vector_type(8))) short  s16x8;
typedef __attribute__((ext_vector_type(4))) short  s16x4;
typedef __attribute__((ext_vector_type(4))) float  f32x4;

__device__ __forceinline__ unsigned short f2b(float f) {
    unsigned u = __float_as_uint(f);
    u = (u + 0x7fffu + ((u >> 16) & 1u)) >> 16;   // RNE fp32 -> bf16
    return (unsigned short)u;
}

// K0: WT[k][h] = bf16(W_bin[h][k])  (transpose so B-frag loads are contiguous)
__global__ void k_prep_w(const float* __restrict__ Wb, unsigned short* __restrict__ WT) {
    int k = blockIdx.x;
    int h = threadIdx.x;
    WT[k * H + h] = f2b(Wb[h * H + k]);
}

// K1: xw[r][k] = sum_h inputs[r][h] * W_atom[h][k]   (r = b*128+i, 2048 rows)
__global__ void k_xw(const float* __restrict__ inp, const float* __restrict__ Wa,
                     float* __restrict__ xw) {
    __shared__ float rows[8][H];
    int r0 = blockIdx.x * 8;
    int t = threadIdx.x;
    #pragma unroll
    for (int r = 0; r < 8; ++r) rows[r][t] = inp[(r0 + r) * H + t];
    __syncthreads();
    float acc[8] = {0.f, 0.f, 0.f, 0.f, 0.f, 0.f, 0.f, 0.f};
    for (int h = 0; h < H; ++h) {
        float wv = Wa[h * H + t];
        #pragma unroll
        for (int r = 0; r < 8; ++r) acc[r] += rows[r][h] * wv;
    }
    #pragma unroll
    for (int r = 0; r < 8; ++r) xw[(r0 + r) * H + t] = acc[r];
}

// K2: per (b, i, j-tile of 64): fused bin@W_bin -> relu -> dot(w_score) -> S,
//     plus atom_pair writes and atomicAdd of inputs[b,i,:]*S into att_context.
__global__ __launch_bounds__(256) void k_main(
        const float* __restrict__ inp, const float* __restrict__ binf,
        const float* __restrict__ xw, const unsigned short* __restrict__ WT,
        const float* __restrict__ b_bin, const float* __restrict__ w_score,
        const float* __restrict__ b_score,
        float* __restrict__ out_ctx, float* __restrict__ out_pair) {
    __shared__ unsigned short Ab[64 * 260];   // bin tile, bf16, padded stride
    __shared__ float base_l[H];               // xw[b,i,:] + b_bin
    __shared__ float wsc_l[H];
    __shared__ float ini_l[H];                // inputs[b,i,:]
    __shared__ float wred[4];
    __shared__ float Sp;

    int bid = blockIdx.x;
    int jt = bid & 1;
    int i  = (bid >> 1) & 127;
    int b  = bid >> 8;
    int t  = threadIdx.x;
    int bi = b * 128 + i;
    int jbase = jt * 64;

    base_l[t] = xw[bi * H + t] + b_bin[t];
    wsc_l[t]  = w_score[t];
    ini_l[t]  = inp[bi * H + t];

    // stage 64x256 fp32 bin tile -> bf16 LDS (row stride 260)
    const float4* bp = (const float4*)(binf + ((long)bi * 128 + jbase) * H);
    #pragma unroll
    for (int it = 0; it < 16; ++it) {
        int idx = it * 256 + t;        // float4 index in tile (16384 floats)
        float4 v = bp[idx];
        int row = idx >> 6;
        int col = (idx & 63) * 4;
        ushort4 w;
        w.x = f2b(v.x); w.y = f2b(v.y); w.z = f2b(v.z); w.w = f2b(v.w);
        *(ushort4*)&Ab[row * 260 + col] = w;
    }
    __syncthreads();

    int wave = t >> 6, lane = t & 63, q = lane >> 4, m16 = lane & 15;
    int colbase = wave * 64;           // waves split the 256 output cols

    f32x4 acc[4][4];
    #pragma unroll
    for (int rt = 0; rt < 4; ++rt)
        #pragma unroll
        for (int ct = 0; ct < 4; ++ct)
            acc[rt][ct] = (f32x4){0.f, 0.f, 0.f, 0.f};

    #pragma unroll
    for (int ks = 0; ks < 8; ++ks) {
        bf16x8 afr[4];
        #pragma unroll
        for (int rt = 0; rt < 4; ++rt) {
            const unsigned short* p = &Ab[(rt * 16 + m16) * 260 + ks * 32 + q * 8];
            s16x4 a0 = *(const s16x4*)p;
            s16x4 a1 = *(const s16x4*)(p + 4);
            s16x8 sv = __builtin_shufflevector(a0, a1, 0, 1, 2, 3, 4, 5, 6, 7);
            afr[rt] = __builtin_bit_cast(bf16x8, sv);
        }
        #pragma unroll
        for (int ct = 0; ct < 4; ++ct) {
            const unsigned short* wp = WT + (colbase + ct * 16 + m16) * H + ks * 32 + q * 8;
            bf16x8 bfr = __builtin_bit_cast(bf16x8, *(const s16x8*)wp);
            #pragma unroll
            for (int rt = 0; rt < 4; ++rt)
                acc[rt][ct] = __builtin_amdgcn_mfma_f32_16x16x32_bf16(afr[rt], bfr, acc[rt][ct], 0, 0, 0);
        }
    }

    // epilogue: hidden = relu(acc + base[k] + xw[b, j, k]); sacc += hidden*w_score[k]
    float sacc = 0.f;
    const float* xwp = xw + ((long)b * 128 + jbase) * H;
    #pragma unroll
    for (int rt = 0; rt < 4; ++rt) {
        #pragma unroll
        for (int ct = 0; ct < 4; ++ct) {
            int k = colbase + ct * 16 + m16;
            float bs = base_l[k], wv = wsc_l[k];
            #pragma unroll
            for (int r = 0; r < 4; ++r) {
                int jl = rt * 16 + q * 4 + r;          // C/D: row = quad*4+reg
                float hv = acc[rt][ct][r] + bs + xwp[jl * H + k];
                hv = fmaxf(hv, 0.f);
                sacc += hv * wv;
            }
        }
    }
    #pragma unroll
    for (int m = 1; m < 64; m <<= 1) sacc += __shfl_xor(sacc, m, 64);
    if (lane == 0) wred[wave] = sacc;
    __syncthreads();
    if (t == 0) Sp = wred[0] + wred[1] + wred[2] + wred[3] + 64.0f * b_score[0];
    __syncthreads();

    // atom_pair writes + ctx atomic
    float iv = ini_l[t];
    float S  = Sp;
    const float* inb  = inp + ((long)b * 128 + jbase) * H;
    float* pout = out_pair + (((long)bi) * 128 + jbase) * H;
    #pragma unroll 4
    for (int j = 0; j < 64; ++j) {
        float v = inb[j * H + t];
        pout[j * H + t] = iv + v;
    }
    atomicAdd(&out_ctx[bi * H + t], iv * S);
}

extern "C" void kernel_launch(void* const* d_in, const int* in_sizes, int n_in,
                              void* d_out, int out_size, void* d_ws, size_t ws_size,
                              hipStream_t stream) {
    const float* inp     = (const float*)d_in[0];   // [16,128,256]
    const float* binf    = (const float*)d_in[1];   // [16,128,128,256]
    const float* W_atom  = (const float*)d_in[2];   // [256,256]
    const float* W_bin   = (const float*)d_in[3];   // [256,256]
    const float* b_bin   = (const float*)d_in[4];   // [256]
    const float* w_score = (const float*)d_in[5];   // [256]
    const float* b_score = (const float*)d_in[6];   // [1]

    float* out_ctx  = (float*)d_out;                 // [16,128,256]
    float* out_pair = (float*)d_out + BB * NN * H;   // [16,128,128,256]

    float* xw = (float*)d_ws;                                        // 2 MB
    unsigned short* WT = (unsigned short*)((char*)d_ws + (size_t)BB * NN * H * 4);

    hipMemsetAsync(d_out, 0, (size_t)BB * NN * H * sizeof(float), stream);
    k_prep_w<<<H, H, 0, stream>>>(W_bin, WT);
    k_xw<<<BB * NN / 8, H, 0, stream>>>(inp, W_atom, xw);
    k_main<<<BB * NN * 2, 256, 0, stream>>>(inp, binf, xw, WT, b_bin, w_score,
                                            b_score, out_ctx, out_pair);
}